// Round 1
// baseline (727.051 us; speedup 1.0000x reference)
//
#include <hip/hip_runtime.h>

#define BB 8
#define CC 64
#define HP 256
#define WP 256
#define PP 65536   // HP*WP
#define QQ 256     // 16*16

// ---------- helpers ----------
__device__ __forceinline__ unsigned encF(float f) {
    unsigned u = __float_as_uint(f);
    return (u & 0x80000000u) ? ~u : (u | 0x80000000u);
}
__device__ __forceinline__ float decF(unsigned u) {
    unsigned b = (u & 0x80000000u) ? (u ^ 0x80000000u) : ~u;
    return __uint_as_float(b);
}

// block of 256 threads, sum of doubles; red4 is __shared__ double[4]
__device__ __forceinline__ double blockSumD(double v, double* red4) {
    int t = threadIdx.x;
    for (int d = 32; d; d >>= 1) v += __shfl_down(v, d, 64);
    __syncthreads();
    if ((t & 63) == 0) red4[t >> 6] = v;
    __syncthreads();
    double r = red4[0] + red4[1] + red4[2] + red4[3];
    __syncthreads();
    return r;
}

// ---------- K0: init atomically-updated ws regions ----------
__global__ void k0_init(unsigned* minmax, int* histpm) {
    int t = threadIdx.x + blockIdx.x * blockDim.x;
    if (t < BB) { minmax[2 * t] = 0xFFFFFFFFu; minmax[2 * t + 1] = 0u; }
    if (t < BB * 256) histpm[t] = 0;
}

// ---------- K1: channel mean of f_p + per-b min/max of the mean image ----------
__global__ __launch_bounds__(256) void k1_fpm(const float* __restrict__ fp,
                                              float* __restrict__ fpm,
                                              unsigned* __restrict__ minmax) {
    int b = blockIdx.y;
    int i4 = blockIdx.x * 256 + threadIdx.x;          // [0, P/4)
    const float4* src = (const float4*)(fp + (size_t)b * CC * PP);
    float sx = 0.f, sy = 0.f, sz = 0.f, sw = 0.f;
    for (int c = 0; c < CC; ++c) {
        float4 v = src[(size_t)c * (PP / 4) + i4];
        sx += v.x; sy += v.y; sz += v.z; sw += v.w;
    }
    const float inv = 1.0f / 64.0f;
    float4 m; m.x = sx * inv; m.y = sy * inv; m.z = sz * inv; m.w = sw * inv;
    ((float4*)(fpm + (size_t)b * PP))[i4] = m;
    float mn = fminf(fminf(m.x, m.y), fminf(m.z, m.w));
    float mx = fmaxf(fmaxf(m.x, m.y), fmaxf(m.z, m.w));
    for (int d = 32; d; d >>= 1) {
        mn = fminf(mn, __shfl_down(mn, d, 64));
        mx = fmaxf(mx, __shfl_down(mx, d, 64));
    }
    __shared__ unsigned smn, smx;
    if (threadIdx.x == 0) { smn = 0xFFFFFFFFu; smx = 0u; }
    __syncthreads();
    if ((threadIdx.x & 63) == 0) { atomicMin(&smn, encF(mn)); atomicMax(&smx, encF(mx)); }
    __syncthreads();
    if (threadIdx.x == 0) { atomicMin(&minmax[2 * b], smn); atomicMax(&minmax[2 * b + 1], smx); }
}

// ---------- K2a: histogram of norm255(f_p_m) ----------
__global__ __launch_bounds__(256) void k2a_hist(const float* __restrict__ fpm,
                                                const unsigned* __restrict__ minmax,
                                                int* __restrict__ histpm) {
    int b = blockIdx.y;
    __shared__ int h[256];
    h[threadIdx.x] = 0;
    __syncthreads();
    float mn = decF(minmax[2 * b]);
    float mx = decF(minmax[2 * b + 1]);
    float dd = mx - mn;
    int i4 = blockIdx.x * 256 + threadIdx.x;
    float4 v = ((const float4*)(fpm + (size_t)b * PP))[i4];
    int b0 = (int)((v.x - mn) / dd * 255.0f);
    int b1 = (int)((v.y - mn) / dd * 255.0f);
    int b2 = (int)((v.z - mn) / dd * 255.0f);
    int b3 = (int)((v.w - mn) / dd * 255.0f);
    b0 = min(max(b0, 0), 255); b1 = min(max(b1, 0), 255);
    b2 = min(max(b2, 0), 255); b3 = min(max(b3, 0), 255);
    atomicAdd(&h[b0], 1); atomicAdd(&h[b1], 1);
    atomicAdd(&h[b2], 1); atomicAdd(&h[b3], 1);
    __syncthreads();
    atomicAdd(&histpm[b * 256 + threadIdx.x], h[threadIdx.x]);
}

// ---------- K2b: entropy of f_p_m_n ----------
__global__ __launch_bounds__(256) void k2b_entropy(const int* __restrict__ histpm,
                                                   float* __restrict__ hpE) {
    __shared__ double red4[4];
    int b = blockIdx.x;
    int n = histpm[b * 256 + threadIdx.x];
    double p = (double)n * (1.0 / 65536.0);
    double term = -(p * log(p + 1e-8));
    double h = blockSumD(term, red4);
    if (threadIdx.x == 0) hpE[b] = (float)h;
}

// ---------- K3: per-(b,c): 16x16 block sums, tent (bilinear-adjoint) pooling,
//                channel sum & sumsq ----------
__global__ __launch_bounds__(256) void k3_chan(const float* __restrict__ fp,
                                               float* __restrict__ cellsum,
                                               float* __restrict__ gtent,
                                               float* __restrict__ chsum,
                                               float* __restrict__ chsumsq) {
    int blk = blockIdx.x, b = blk >> 6, c = blk & 63;
    int x = threadIdx.x, s = x >> 4, r = x & 15;
    const float* src = fp + (size_t)(b * CC + c) * PP;
    __shared__ float tentL[256];
    __shared__ double red4[4];
    tentL[x] = 0.0f;
    __syncthreads();
    // x-direction tent weights into columns s-1 (wm), s (w0), s+1 (wp)
    float wm, w0, wp;
    if (x <= 7)        { wm = 0.f; w0 = 1.f; wp = 0.f; }
    else if (x >= 248) { wm = 0.f; w0 = 1.f; wp = 0.f; }
    else if (r < 8)    { float fx = ((float)r + 8.5f) * 0.0625f; wm = 1.f - fx; w0 = fx;       wp = 0.f; }
    else               { float fx = ((float)r - 7.5f) * 0.0625f; wm = 0.f;      w0 = 1.f - fx; wp = fx;  }
    double sum = 0.0, ssq = 0.0;
    float am = 0.f, a0 = 0.f, ap = 0.f, cs = 0.f;
    for (int y = 0; y < 256; ++y) {
        float v = src[y * 256 + x];
        sum += (double)v;
        ssq += (double)v * (double)v;
        cs  += v;
        int q = y >> 4, ry = y & 15;
        if ((q == 0 && ry < 8) || (q == 15 && ry >= 8)) {
            a0 += v;
        } else if (ry < 8) {
            float fy = ((float)ry + 8.5f) * 0.0625f;
            am += (1.f - fy) * v; a0 += fy * v;
        } else {
            float fy = ((float)ry - 7.5f) * 0.0625f;
            a0 += (1.f - fy) * v; ap += fy * v;
        }
        if (ry == 15) {
            float vals[10];
            vals[0] = am * wm; vals[1] = am * w0; vals[2] = am * wp;
            vals[3] = a0 * wm; vals[4] = a0 * w0; vals[5] = a0 * wp;
            vals[6] = ap * wm; vals[7] = ap * w0; vals[8] = ap * wp;
            vals[9] = cs;
#pragma unroll
            for (int d = 8; d; d >>= 1) {
#pragma unroll
                for (int k2 = 0; k2 < 10; ++k2) vals[k2] += __shfl_down(vals[k2], d, 16);
            }
            if (r == 0) {
                if (q > 0) {
                    if (s > 0)  atomicAdd(&tentL[(q - 1) * 16 + (s - 1)], vals[0]);
                    atomicAdd(&tentL[(q - 1) * 16 + s], vals[1]);
                    if (s < 15) atomicAdd(&tentL[(q - 1) * 16 + (s + 1)], vals[2]);
                }
                if (s > 0)  atomicAdd(&tentL[q * 16 + (s - 1)], vals[3]);
                atomicAdd(&tentL[q * 16 + s], vals[4]);
                if (s < 15) atomicAdd(&tentL[q * 16 + (s + 1)], vals[5]);
                if (q < 15) {
                    if (s > 0)  atomicAdd(&tentL[(q + 1) * 16 + (s - 1)], vals[6]);
                    atomicAdd(&tentL[(q + 1) * 16 + s], vals[7]);
                    if (s < 15) atomicAdd(&tentL[(q + 1) * 16 + (s + 1)], vals[8]);
                }
                cellsum[(size_t)(b * CC + c) * QQ + q * 16 + s] = vals[9];
            }
            am = a0 = ap = cs = 0.f;
        }
    }
    __syncthreads();
    gtent[(size_t)(b * CC + c) * QQ + x] = tentL[x];
    double st = blockSumD(sum, red4);
    double sq = blockSumD(ssq, red4);
    if (x == 0) { chsum[b * CC + c] = (float)st; chsumsq[b * CC + c] = (float)sq; }
}

// ---------- K4: per-(b,c) f_ms: norm255 bins, histogram, entropy,
//                ||ms_u - mean||  via tent-Gram quadratic form, sum ----------
__global__ __launch_bounds__(256) void k4_ms(const float* __restrict__ fms,
                                             int* __restrict__ msn,
                                             int* __restrict__ histms,
                                             float* __restrict__ hmsE,
                                             float* __restrict__ naArr,
                                             float* __restrict__ mssum) {
    int blk = blockIdx.x, b = blk >> 6, c = blk & 63, t = threadIdx.x;
    __shared__ float m[256];
    __shared__ int hist[256];
    __shared__ double red4[4];
    __shared__ double U[256];
    __shared__ unsigned umn, umx;
    float v = fms[(size_t)(b * CC + c) * QQ + t];
    m[t] = v;
    hist[t] = 0;
    if (t == 0) { umn = 0xFFFFFFFFu; umx = 0u; }
    float mn = v, mx = v;
    for (int d = 32; d; d >>= 1) {
        mn = fminf(mn, __shfl_down(mn, d, 64));
        mx = fmaxf(mx, __shfl_down(mx, d, 64));
    }
    __syncthreads();
    if ((t & 63) == 0) { atomicMin(&umn, encF(mn)); atomicMax(&umx, encF(mx)); }
    __syncthreads();
    mn = decF(umn); mx = decF(umx);
    int bin = (int)((v - mn) / (mx - mn) * 255.0f);
    bin = min(max(bin, 0), 255);
    msn[(size_t)(b * CC + c) * QQ + t] = bin;
    atomicAdd(&hist[bin], 1);
    __syncthreads();
    histms[(size_t)(b * CC + c) * QQ + t] = hist[t];
    float pf = (float)hist[t] * (1.0f / 256.0f);
    double term = -((double)pf * log((double)pf + 1e-8));
    double h = blockSumD(term, red4);
    if (t == 0) hmsE[b * CC + c] = (float)h;
    // quadratic form vec(M)^T (Ky (x) Kx) vec(M)
    int i = t >> 4, j = t & 15;
    double kdj = (j == 0 || j == 15) ? 13.328125 : 10.65625;
    double mv = (double)m[t];
    double uu = kdj * mv + 2.671875 * ((j > 0 ? (double)m[t - 1] : 0.0) +
                                       (j < 15 ? (double)m[t + 1] : 0.0));
    U[t] = uu;
    __syncthreads();
    double kdi = (i == 0 || i == 15) ? 13.328125 : 10.65625;
    double vv = kdi * U[t] + 2.671875 * ((i > 0 ? U[t - 16] : 0.0) +
                                         (i < 15 ? U[t + 16] : 0.0));
    double sq = blockSumD(mv * vv, red4);
    double msm = blockSumD(mv, red4);
    if (t == 0) {
        mssum[b * CC + c] = (float)msm;
        double meanu = msm * (1.0 / 256.0);
        double na2 = sq - 65536.0 * meanu * meanu;
        naArr[b * CC + c] = (float)sqrt(na2 > 0.0 ? na2 : 0.0);
    }
}

// ---------- K5: f_p_a = mean over c of pooled; norm255 bins + histogram ----------
__global__ __launch_bounds__(256) void k5_pa(const float* __restrict__ cellsum,
                                             int* __restrict__ pan,
                                             int* __restrict__ histp) {
    int b = blockIdx.x, t = threadIdx.x;
    __shared__ int hist[256];
    __shared__ unsigned umn, umx;
    hist[t] = 0;
    if (t == 0) { umn = 0xFFFFFFFFu; umx = 0u; }
    double acc = 0.0;
    for (int c = 0; c < CC; ++c) acc += (double)cellsum[(size_t)(b * CC + c) * QQ + t];
    float pa = (float)(acc * (1.0 / 256.0) * (1.0 / 64.0));
    float mn = pa, mx = pa;
    for (int d = 32; d; d >>= 1) {
        mn = fminf(mn, __shfl_down(mn, d, 64));
        mx = fmaxf(mx, __shfl_down(mx, d, 64));
    }
    __syncthreads();
    if ((t & 63) == 0) { atomicMin(&umn, encF(mn)); atomicMax(&umx, encF(mx)); }
    __syncthreads();
    mn = decF(umn); mx = decF(umx);
    int bin = (int)((pa - mn) / (mx - mn) * 255.0f);
    bin = min(max(bin, 0), 255);
    pan[b * QQ + t] = bin;
    atomicAdd(&hist[bin], 1);
    __syncthreads();
    histp[b * 256 + t] = hist[t];
}

// ---------- K6: joint entropy per (b,c) ----------
__global__ __launch_bounds__(256) void k6_joint(const int* __restrict__ msn,
                                                const int* __restrict__ pan,
                                                const int* __restrict__ histms,
                                                const int* __restrict__ histp,
                                                float* __restrict__ hjoint) {
    int blk = blockIdx.x, b = blk >> 6, c = blk & 63, t = threadIdx.x;
    __shared__ int key[256], hms[256], hp[256];
    __shared__ double red4[4];
    int iv = msn[(size_t)(b * CC + c) * QQ + t];
    int jv = pan[b * QQ + t];
    key[t] = (iv << 8) | jv;
    hms[t] = histms[(size_t)(b * CC + c) * QQ + t];
    hp[t] = histp[b * 256 + t];
    __syncthreads();
    // bitmap: for row i==t, mark columns j with J[i,j] > 0
    unsigned long long w0_ = 0, w1_ = 0, w2_ = 0, w3_ = 0;
    for (int p = 0; p < 256; ++p) {
        int k2 = key[p];
        if ((k2 >> 8) == t) {
            int j = k2 & 255;
            unsigned long long bit = 1ull << (j & 63);
            int w = j >> 6;
            if (w == 0) w0_ |= bit; else if (w == 1) w1_ |= bit;
            else if (w == 2) w2_ |= bit; else w3_ |= bit;
        }
    }
    double acc = 0.0;
    int basei = 256 - hms[t];
    unsigned long long words[4] = { w0_, w1_, w2_, w3_ };
#pragma unroll
    for (int w = 0; w < 4; ++w) {
        unsigned long long word = words[w];
        for (int jj = 0; jj < 64; ++jj) {
            if (!((word >> jj) & 1ull)) {
                int cnt = basei - hp[w * 64 + jj];
                float pf = (float)cnt * (1.0f / 65536.0f);
                acc -= (double)pf * log((double)pf + 1e-8);
            }
        }
    }
    // correction: cells with J>0, counted once (first pixel with that key)
    int myk = key[t], n = 0; bool first = true;
    for (int p = 0; p < 256; ++p) {
        int k2 = key[p];
        if (k2 == myk) { n++; if (p < t) first = false; }
    }
    if (first) {
        int cnt = 2 * n + 256 - hms[myk >> 8] - hp[myk & 255];
        float pf = (float)cnt * (1.0f / 65536.0f);
        acc -= (double)pf * log((double)pf + 1e-8);
    }
    double h = blockSumD(acc, red4);
    if (t == 0) hjoint[b * CC + c] = (float)h;
}

// ---------- K7: mi softmax + rel_ms ----------
__global__ __launch_bounds__(256) void k7_relms(const float* __restrict__ fms,
                                                const float* __restrict__ hmsE,
                                                const float* __restrict__ hpE,
                                                const float* __restrict__ hjoint,
                                                float* __restrict__ out2) {
    int b = blockIdx.x, t = threadIdx.x;
    __shared__ double mi[64];
    if (t < 64) mi[t] = (double)hpE[b] + (double)hmsE[b * CC + t] - (double)hjoint[b * CC + t];
    __syncthreads();
    if (t == 0) {
        double mxv = mi[0];
        for (int c2 = 1; c2 < 64; ++c2) if (mi[c2] > mxv) mxv = mi[c2];
        double s = 0.0;
        for (int c2 = 0; c2 < 64; ++c2) { mi[c2] = exp(mi[c2] - mxv); s += mi[c2]; }
        for (int c2 = 0; c2 < 64; ++c2) mi[c2] /= s;
    }
    __syncthreads();
    const float* src = fms + (size_t)b * CC * QQ;
    float* dst = out2 + (size_t)b * CC * QQ;
    for (int e = t; e < CC * QQ; e += 256) {
        float v = src[e];
        float miv = (float)mi[e >> 8];
        dst[e] = v + v * miv;
    }
}

// ---------- K8: similarity row max/argmax per (b,c) ----------
__global__ __launch_bounds__(256) void k8_smax(const float* __restrict__ fms,
                                               const float* __restrict__ gtent,
                                               const float* __restrict__ mssum,
                                               const float* __restrict__ chsum,
                                               const float* __restrict__ chsumsq,
                                               const float* __restrict__ naArr,
                                               float* __restrict__ mxArr,
                                               int* __restrict__ idxArr) {
    int blk = blockIdx.x, b = blk >> 6, c = blk & 63, t = threadIdx.x;
    __shared__ float msrow[256];
    __shared__ double part[256];
    __shared__ double sval[64];
    msrow[t] = fms[(size_t)(b * CC + c) * QQ + t];
    __syncthreads();
    int d = t >> 2, pr = t & 3;
    const float* g = gtent + (size_t)(b * CC + d) * QQ + pr * 64;
    const float* mr = msrow + pr * 64;
    double acc = 0.0;
    for (int q2 = 0; q2 < 64; ++q2) acc += (double)mr[q2] * (double)g[q2];
    part[t] = acc;
    __syncthreads();
    if (t < 64) {
        double meanu = (double)mssum[b * CC + c] * (1.0 / 256.0);
        double meanp = (double)chsum[b * CC + t] * (1.0 / 65536.0);
        sval[t] = part[t * 4] + part[t * 4 + 1] + part[t * 4 + 2] + part[t * 4 + 3]
                  - 65536.0 * meanu * meanp;
    }
    __syncthreads();
    if (t == 0) {
        double best = sval[0]; int bi2 = 0;
        for (int dd = 1; dd < 64; ++dd) { if (sval[dd] > best) { best = sval[dd]; bi2 = dd; } }
        double nac = (double)naArr[b * CC + c];
        double sc_ = (double)chsum[b * CC + c];
        double sq_ = (double)chsumsq[b * CC + c];
        double nb2 = sq_ - sc_ * sc_ * (1.0 / 65536.0);
        double nbc = sqrt(nb2 > 0.0 ? nb2 : 0.0);
        mxArr[b * CC + c] = (float)(best * 100.0 / (nac * nbc));
        idxArr[b * CC + c] = bi2;
    }
}

// ---------- K9: scores, grouping, min_k, stable sort, selection weights ----------
__global__ __launch_bounds__(64) void k9_small(const float* __restrict__ mxArr,
                                               const int* __restrict__ idxArr,
                                               float* __restrict__ wsel,
                                               int* __restrict__ chanA,
                                               int* __restrict__ minkA) {
    __shared__ double sc[8][64];
    __shared__ double gs[8][64];
    __shared__ int cnt[8][64];
    __shared__ int ord[8][64];
    __shared__ int uarr[8];
    __shared__ int mkS;
    int t = threadIdx.x;
    if (t < 8) {
        int b = t;
        double mxv = -1e300;
        for (int c2 = 0; c2 < 64; ++c2) {
            double v = (double)mxArr[b * 64 + c2];
            sc[b][c2] = v;
            if (v > mxv) mxv = v;
        }
        double s = 0.0;
        for (int c2 = 0; c2 < 64; ++c2) { double e = exp(sc[b][c2] - mxv); sc[b][c2] = e; s += e; }
        for (int c2 = 0; c2 < 64; ++c2) { sc[b][c2] /= s; gs[b][c2] = 0.0; cnt[b][c2] = 0; }
        for (int c2 = 0; c2 < 64; ++c2) { int v = idxArr[b * 64 + c2]; gs[b][v] += sc[b][c2]; cnt[b][v] += 1; }
        int u = 0;
        for (int c2 = 0; c2 < 64; ++c2) if (cnt[b][c2] > 0) u++;
        uarr[b] = u;
    }
    __syncthreads();
    if (t == 0) {
        int k = uarr[0];
        for (int b2 = 1; b2 < 8; ++b2) if (uarr[b2] < k) k = uarr[b2];
        mkS = (k + 1) >> 1;
        minkA[0] = mkS;
    }
    __syncthreads();
    if (t < 8) {
        int b = t;
        // stable descending argsort: ties -> smaller index first
        for (int c2 = 0; c2 < 64; ++c2) {
            int rk = 0;
            for (int c3 = 0; c3 < 64; ++c3) {
                double a = gs[b][c3], bb = gs[b][c2];
                if (a > bb || (a == bb && c3 < c2)) rk++;
            }
            ord[b][rk] = c2;
        }
        int mk = mkS;
        double z0 = gs[b][ord[b][0]];
        double s = 0.0;
        for (int i2 = 0; i2 < mk; ++i2) s += exp(gs[b][ord[b][i2]] - z0);
        for (int i2 = 0; i2 < mk; ++i2) {
            wsel[b * 64 + i2] = (float)(exp(gs[b][ord[b][i2]] - z0) / s);
            chanA[b * 64 + i2] = ord[b][i2];
        }
    }
}

// ---------- K10: rel_p = f_p * (1 + mask) ----------
__global__ __launch_bounds__(256) void k10_relp(const float* __restrict__ fp,
                                                const float* __restrict__ wsel,
                                                const int* __restrict__ chanA,
                                                const int* __restrict__ minkA,
                                                float* __restrict__ outp) {
    int b = blockIdx.y;
    int i4 = blockIdx.x * 256 + threadIdx.x;      // [0, P/4)
    int mk = minkA[0];
    const float4* src = (const float4*)(fp + (size_t)b * CC * PP);
    float mx0 = 0.f, mx1 = 0.f, mx2 = 0.f, mx3 = 0.f;
    for (int i = 0; i < mk; ++i) {
        int ch = chanA[b * 64 + i];
        float wv = wsel[b * 64 + i];
        float4 v = src[(size_t)ch * (PP / 4) + i4];
        mx0 += wv * (1.0f / (1.0f + expf(-v.x)));
        mx1 += wv * (1.0f / (1.0f + expf(-v.y)));
        mx2 += wv * (1.0f / (1.0f + expf(-v.z)));
        mx3 += wv * (1.0f / (1.0f + expf(-v.w)));
    }
    float4* dst = (float4*)(outp + (size_t)b * CC * PP);
    for (int c2 = 0; c2 < CC; ++c2) {
        float4 v = src[(size_t)c2 * (PP / 4) + i4];
        float4 o;
        o.x = v.x + v.x * mx0;
        o.y = v.y + v.y * mx1;
        o.z = v.z + v.z * mx2;
        o.w = v.w + v.w * mx3;
        dst[(size_t)c2 * (PP / 4) + i4] = o;
    }
}

extern "C" void kernel_launch(void* const* d_in, const int* in_sizes, int n_in,
                              void* d_out, int out_size, void* d_ws, size_t ws_size,
                              hipStream_t stream) {
    const float* fp = (const float*)d_in[0];   // [8,64,256,256]
    const float* fms = (const float*)d_in[1];  // [8,64,16,16]
    float* out = (float*)d_out;

    char* p = (char*)d_ws;
    auto alloc = [&](size_t bytes) { void* r = (void*)p; p += (bytes + 255) & ~(size_t)255; return r; };

    float* fpm      = (float*)alloc((size_t)BB * PP * 4);        // 2 MB
    float* cellsum  = (float*)alloc((size_t)BB * CC * QQ * 4);   // 512 KB (block SUMS)
    float* gtent    = (float*)alloc((size_t)BB * CC * QQ * 4);   // 512 KB
    float* chsum    = (float*)alloc((size_t)BB * CC * 4);
    float* chsumsq  = (float*)alloc((size_t)BB * CC * 4);
    unsigned* minmax= (unsigned*)alloc((size_t)BB * 2 * 4);
    int* histpm     = (int*)alloc((size_t)BB * 256 * 4);
    int* msn        = (int*)alloc((size_t)BB * CC * QQ * 4);     // 512 KB
    int* histms     = (int*)alloc((size_t)BB * CC * 256 * 4);    // 512 KB
    int* histp      = (int*)alloc((size_t)BB * 256 * 4);
    int* pan        = (int*)alloc((size_t)BB * QQ * 4);
    float* hmsE     = (float*)alloc((size_t)BB * CC * 4);
    float* hpE      = (float*)alloc((size_t)BB * 4);
    float* hjoint   = (float*)alloc((size_t)BB * CC * 4);
    float* naArr    = (float*)alloc((size_t)BB * CC * 4);
    float* mssum    = (float*)alloc((size_t)BB * CC * 4);
    float* mxArr    = (float*)alloc((size_t)BB * CC * 4);
    int* idxArr     = (int*)alloc((size_t)BB * CC * 4);
    float* wsel     = (float*)alloc((size_t)BB * CC * 4);
    int* chanA      = (int*)alloc((size_t)BB * CC * 4);
    int* minkA      = (int*)alloc(256);

    float* out_relp  = out;                                      // [8,64,256,256]
    float* out_relms = out + (size_t)BB * CC * PP;               // [8,64,16,16]

    k0_init<<<8, 256, 0, stream>>>(minmax, histpm);
    k1_fpm<<<dim3(64, 8), 256, 0, stream>>>(fp, fpm, minmax);
    k2a_hist<<<dim3(64, 8), 256, 0, stream>>>(fpm, minmax, histpm);
    k2b_entropy<<<8, 256, 0, stream>>>(histpm, hpE);
    k3_chan<<<512, 256, 0, stream>>>(fp, cellsum, gtent, chsum, chsumsq);
    k4_ms<<<512, 256, 0, stream>>>(fms, msn, histms, hmsE, naArr, mssum);
    k5_pa<<<8, 256, 0, stream>>>(cellsum, pan, histp);
    k6_joint<<<512, 256, 0, stream>>>(msn, pan, histms, histp, hjoint);
    k7_relms<<<8, 256, 0, stream>>>(fms, hmsE, hpE, hjoint, out_relms);
    k8_smax<<<512, 256, 0, stream>>>(fms, gtent, mssum, chsum, chsumsq, naArr, mxArr, idxArr);
    k9_small<<<1, 64, 0, stream>>>(mxArr, idxArr, wsel, chanA, minkA);
    k10_relp<<<dim3(64, 8), 256, 0, stream>>>(fp, wsel, chanA, minkA, out_relp);
}

// Round 2
// 414.302 us; speedup vs baseline: 1.7549x; 1.7549x over previous
//
#include <hip/hip_runtime.h>

#define BB 8
#define CC 64
#define HP 256
#define WP 256
#define PP 65536   // HP*WP
#define QQ 256     // 16*16

// ---------- helpers ----------
__device__ __forceinline__ unsigned encF(float f) {
    unsigned u = __float_as_uint(f);
    return (u & 0x80000000u) ? ~u : (u | 0x80000000u);
}
__device__ __forceinline__ float decF(unsigned u) {
    unsigned b = (u & 0x80000000u) ? (u ^ 0x80000000u) : ~u;
    return __uint_as_float(b);
}

// block of 256 threads, sum of doubles; red4 is __shared__ double[4]
__device__ __forceinline__ double blockSumD(double v, double* red4) {
    int t = threadIdx.x;
    for (int d = 32; d; d >>= 1) v += __shfl_down(v, d, 64);
    __syncthreads();
    if ((t & 63) == 0) red4[t >> 6] = v;
    __syncthreads();
    double r = red4[0] + red4[1] + red4[2] + red4[3];
    __syncthreads();
    return r;
}

// ---------- K0: init atomically-updated ws regions ----------
__global__ void k0_init(unsigned* minmax, int* histpm) {
    int t = threadIdx.x + blockIdx.x * blockDim.x;
    if (t < BB) { minmax[2 * t] = 0xFFFFFFFFu; minmax[2 * t + 1] = 0u; }
    if (t < BB * 256) histpm[t] = 0;
}

// ---------- K1: channel mean of f_p + per-b min/max of the mean image ----------
__global__ __launch_bounds__(256) void k1_fpm(const float* __restrict__ fp,
                                              float* __restrict__ fpm,
                                              unsigned* __restrict__ minmax) {
    int b = blockIdx.y;
    int i4 = blockIdx.x * 256 + threadIdx.x;          // [0, P/4)
    const float4* src = (const float4*)(fp + (size_t)b * CC * PP);
    float sx = 0.f, sy = 0.f, sz = 0.f, sw = 0.f;
#pragma unroll 8
    for (int c = 0; c < CC; ++c) {
        float4 v = src[(size_t)c * (PP / 4) + i4];
        sx += v.x; sy += v.y; sz += v.z; sw += v.w;
    }
    const float inv = 1.0f / 64.0f;
    float4 m; m.x = sx * inv; m.y = sy * inv; m.z = sz * inv; m.w = sw * inv;
    ((float4*)(fpm + (size_t)b * PP))[i4] = m;
    float mn = fminf(fminf(m.x, m.y), fminf(m.z, m.w));
    float mx = fmaxf(fmaxf(m.x, m.y), fmaxf(m.z, m.w));
    for (int d = 32; d; d >>= 1) {
        mn = fminf(mn, __shfl_down(mn, d, 64));
        mx = fmaxf(mx, __shfl_down(mx, d, 64));
    }
    __shared__ unsigned smn, smx;
    if (threadIdx.x == 0) { smn = 0xFFFFFFFFu; smx = 0u; }
    __syncthreads();
    if ((threadIdx.x & 63) == 0) { atomicMin(&smn, encF(mn)); atomicMax(&smx, encF(mx)); }
    __syncthreads();
    if (threadIdx.x == 0) { atomicMin(&minmax[2 * b], smn); atomicMax(&minmax[2 * b + 1], smx); }
}

// ---------- K2a: histogram of norm255(f_p_m) ----------
__global__ __launch_bounds__(256) void k2a_hist(const float* __restrict__ fpm,
                                                const unsigned* __restrict__ minmax,
                                                int* __restrict__ histpm) {
    int b = blockIdx.y;
    __shared__ int h[256];
    h[threadIdx.x] = 0;
    __syncthreads();
    float mn = decF(minmax[2 * b]);
    float mx = decF(minmax[2 * b + 1]);
    float dd = mx - mn;
    int i4 = blockIdx.x * 256 + threadIdx.x;
    float4 v = ((const float4*)(fpm + (size_t)b * PP))[i4];
    int b0 = (int)((v.x - mn) / dd * 255.0f);
    int b1 = (int)((v.y - mn) / dd * 255.0f);
    int b2 = (int)((v.z - mn) / dd * 255.0f);
    int b3 = (int)((v.w - mn) / dd * 255.0f);
    b0 = min(max(b0, 0), 255); b1 = min(max(b1, 0), 255);
    b2 = min(max(b2, 0), 255); b3 = min(max(b3, 0), 255);
    atomicAdd(&h[b0], 1); atomicAdd(&h[b1], 1);
    atomicAdd(&h[b2], 1); atomicAdd(&h[b3], 1);
    __syncthreads();
    atomicAdd(&histpm[b * 256 + threadIdx.x], h[threadIdx.x]);
}

// ---------- K2b: entropy of f_p_m_n ----------
__global__ __launch_bounds__(256) void k2b_entropy(const int* __restrict__ histpm,
                                                   float* __restrict__ hpE) {
    __shared__ double red4[4];
    int b = blockIdx.x;
    int n = histpm[b * 256 + threadIdx.x];
    float p = (float)n * (1.0f / 65536.0f);
    double term = -(double)(p * __logf(p + 1e-8f));
    double h = blockSumD(term, red4);
    if (threadIdx.x == 0) hpE[b] = (float)h;
}

// ---------- K3: per-(b,c): 16x16 block sums, tent (bilinear-adjoint) pooling,
//                channel sum & sumsq ----------
__global__ __launch_bounds__(256) void k3_chan(const float* __restrict__ fp,
                                               float* __restrict__ cellsum,
                                               float* __restrict__ gtent,
                                               float* __restrict__ chsum,
                                               float* __restrict__ chsumsq) {
    int blk = blockIdx.x, b = blk >> 6, c = blk & 63;
    int x = threadIdx.x, s = x >> 4, r = x & 15;
    const float* src = fp + (size_t)(b * CC + c) * PP;
    __shared__ float tentL[256];
    __shared__ double red4[4];
    tentL[x] = 0.0f;
    __syncthreads();
    // x-direction tent weights into columns s-1 (wm), s (w0), s+1 (wp)
    float wm, w0, wp;
    if (x <= 7)        { wm = 0.f; w0 = 1.f; wp = 0.f; }
    else if (x >= 248) { wm = 0.f; w0 = 1.f; wp = 0.f; }
    else if (r < 8)    { float fx = ((float)r + 8.5f) * 0.0625f; wm = 1.f - fx; w0 = fx;       wp = 0.f; }
    else               { float fx = ((float)r - 7.5f) * 0.0625f; wm = 0.f;      w0 = 1.f - fx; wp = fx;  }
    double sum = 0.0, ssq = 0.0;
    for (int q = 0; q < 16; ++q) {
        float am = 0.f, a0 = 0.f, ap = 0.f, cs = 0.f;
#pragma unroll
        for (int ry = 0; ry < 16; ++ry) {
            float v = src[(q * 16 + ry) * 256 + x];
            sum += (double)v;
            ssq += (double)v * (double)v;
            cs  += v;
            if ((q == 0 && ry < 8) || (q == 15 && ry >= 8)) {
                a0 += v;
            } else if (ry < 8) {
                float fy = ((float)ry + 8.5f) * 0.0625f;
                am += (1.f - fy) * v; a0 += fy * v;
            } else {
                float fy = ((float)ry - 7.5f) * 0.0625f;
                a0 += (1.f - fy) * v; ap += fy * v;
            }
        }
        float vals[10];
        vals[0] = am * wm; vals[1] = am * w0; vals[2] = am * wp;
        vals[3] = a0 * wm; vals[4] = a0 * w0; vals[5] = a0 * wp;
        vals[6] = ap * wm; vals[7] = ap * w0; vals[8] = ap * wp;
        vals[9] = cs;
#pragma unroll
        for (int d = 8; d; d >>= 1) {
#pragma unroll
            for (int k2 = 0; k2 < 10; ++k2) vals[k2] += __shfl_down(vals[k2], d, 16);
        }
        if (r == 0) {
            if (q > 0) {
                if (s > 0)  atomicAdd(&tentL[(q - 1) * 16 + (s - 1)], vals[0]);
                atomicAdd(&tentL[(q - 1) * 16 + s], vals[1]);
                if (s < 15) atomicAdd(&tentL[(q - 1) * 16 + (s + 1)], vals[2]);
            }
            if (s > 0)  atomicAdd(&tentL[q * 16 + (s - 1)], vals[3]);
            atomicAdd(&tentL[q * 16 + s], vals[4]);
            if (s < 15) atomicAdd(&tentL[q * 16 + (s + 1)], vals[5]);
            if (q < 15) {
                if (s > 0)  atomicAdd(&tentL[(q + 1) * 16 + (s - 1)], vals[6]);
                atomicAdd(&tentL[(q + 1) * 16 + s], vals[7]);
                if (s < 15) atomicAdd(&tentL[(q + 1) * 16 + (s + 1)], vals[8]);
            }
            cellsum[(size_t)(b * CC + c) * QQ + q * 16 + s] = vals[9];
        }
    }
    __syncthreads();
    gtent[(size_t)(b * CC + c) * QQ + x] = tentL[x];
    double st = blockSumD(sum, red4);
    double sq = blockSumD(ssq, red4);
    if (x == 0) { chsum[b * CC + c] = (float)st; chsumsq[b * CC + c] = (float)sq; }
}

// ---------- K4: per-(b,c) f_ms: norm255 bins, histogram, entropy,
//                ||ms_u - mean||  via tent-Gram quadratic form, sum ----------
__global__ __launch_bounds__(256) void k4_ms(const float* __restrict__ fms,
                                             int* __restrict__ msn,
                                             int* __restrict__ histms,
                                             float* __restrict__ hmsE,
                                             float* __restrict__ naArr,
                                             float* __restrict__ mssum) {
    int blk = blockIdx.x, b = blk >> 6, c = blk & 63, t = threadIdx.x;
    __shared__ float m[256];
    __shared__ int hist[256];
    __shared__ double red4[4];
    __shared__ double U[256];
    __shared__ unsigned umn, umx;
    float v = fms[(size_t)(b * CC + c) * QQ + t];
    m[t] = v;
    hist[t] = 0;
    if (t == 0) { umn = 0xFFFFFFFFu; umx = 0u; }
    float mn = v, mx = v;
    for (int d = 32; d; d >>= 1) {
        mn = fminf(mn, __shfl_down(mn, d, 64));
        mx = fmaxf(mx, __shfl_down(mx, d, 64));
    }
    __syncthreads();
    if ((t & 63) == 0) { atomicMin(&umn, encF(mn)); atomicMax(&umx, encF(mx)); }
    __syncthreads();
    mn = decF(umn); mx = decF(umx);
    int bin = (int)((v - mn) / (mx - mn) * 255.0f);
    bin = min(max(bin, 0), 255);
    msn[(size_t)(b * CC + c) * QQ + t] = bin;
    atomicAdd(&hist[bin], 1);
    __syncthreads();
    histms[(size_t)(b * CC + c) * QQ + t] = hist[t];
    float pf = (float)hist[t] * (1.0f / 256.0f);
    double term = -(double)(pf * __logf(pf + 1e-8f));
    double h = blockSumD(term, red4);
    if (t == 0) hmsE[b * CC + c] = (float)h;
    // quadratic form vec(M)^T (Ky (x) Kx) vec(M)
    int i = t >> 4, j = t & 15;
    double kdj = (j == 0 || j == 15) ? 13.328125 : 10.65625;
    double mv = (double)m[t];
    double uu = kdj * mv + 2.671875 * ((j > 0 ? (double)m[t - 1] : 0.0) +
                                       (j < 15 ? (double)m[t + 1] : 0.0));
    U[t] = uu;
    __syncthreads();
    double kdi = (i == 0 || i == 15) ? 13.328125 : 10.65625;
    double vv = kdi * U[t] + 2.671875 * ((i > 0 ? U[t - 16] : 0.0) +
                                         (i < 15 ? U[t + 16] : 0.0));
    double sq = blockSumD(mv * vv, red4);
    double msm = blockSumD(mv, red4);
    if (t == 0) {
        mssum[b * CC + c] = (float)msm;
        double meanu = msm * (1.0 / 256.0);
        double na2 = sq - 65536.0 * meanu * meanu;
        naArr[b * CC + c] = (float)sqrt(na2 > 0.0 ? na2 : 0.0);
    }
}

// ---------- K5: f_p_a = mean over c of pooled; norm255 bins + histogram ----------
__global__ __launch_bounds__(256) void k5_pa(const float* __restrict__ cellsum,
                                             int* __restrict__ pan,
                                             int* __restrict__ histp) {
    int b = blockIdx.x, t = threadIdx.x;
    __shared__ int hist[256];
    __shared__ unsigned umn, umx;
    hist[t] = 0;
    if (t == 0) { umn = 0xFFFFFFFFu; umx = 0u; }
    double acc = 0.0;
    for (int c = 0; c < CC; ++c) acc += (double)cellsum[(size_t)(b * CC + c) * QQ + t];
    float pa = (float)(acc * (1.0 / 256.0) * (1.0 / 64.0));
    float mn = pa, mx = pa;
    for (int d = 32; d; d >>= 1) {
        mn = fminf(mn, __shfl_down(mn, d, 64));
        mx = fmaxf(mx, __shfl_down(mx, d, 64));
    }
    __syncthreads();
    if ((t & 63) == 0) { atomicMin(&umn, encF(mn)); atomicMax(&umx, encF(mx)); }
    __syncthreads();
    mn = decF(umn); mx = decF(umx);
    int bin = (int)((pa - mn) / (mx - mn) * 255.0f);
    bin = min(max(bin, 0), 255);
    pan[b * QQ + t] = bin;
    atomicAdd(&hist[bin], 1);
    __syncthreads();
    histp[b * 256 + t] = hist[t];
}

// ---------- K6: joint entropy per (b,c) ----------
__global__ __launch_bounds__(256) void k6_joint(const int* __restrict__ msn,
                                                const int* __restrict__ pan,
                                                const int* __restrict__ histms,
                                                const int* __restrict__ histp,
                                                float* __restrict__ hjoint) {
    int blk = blockIdx.x, b = blk >> 6, c = blk & 63, t = threadIdx.x;
    __shared__ int key[256], hms[256], hp[256];
    __shared__ double red4[4];
    int iv = msn[(size_t)(b * CC + c) * QQ + t];
    int jv = pan[b * QQ + t];
    key[t] = (iv << 8) | jv;
    hms[t] = histms[(size_t)(b * CC + c) * QQ + t];
    hp[t] = histp[b * 256 + t];
    __syncthreads();
    // bitmap: for row i==t, mark columns j with J[i,j] > 0
    unsigned long long w0_ = 0, w1_ = 0, w2_ = 0, w3_ = 0;
    for (int p = 0; p < 256; ++p) {
        int k2 = key[p];
        if ((k2 >> 8) == t) {
            int j = k2 & 255;
            unsigned long long bit = 1ull << (j & 63);
            int w = j >> 6;
            if (w == 0) w0_ |= bit; else if (w == 1) w1_ |= bit;
            else if (w == 2) w2_ |= bit; else w3_ |= bit;
        }
    }
    double acc = 0.0;
    int basei = 256 - hms[t];
    unsigned long long words[4] = { w0_, w1_, w2_, w3_ };
#pragma unroll
    for (int w = 0; w < 4; ++w) {
        unsigned long long word = words[w];
        for (int jj = 0; jj < 64; ++jj) {
            if (!((word >> jj) & 1ull)) {
                int cnt = basei - hp[w * 64 + jj];
                float pf = (float)cnt * (1.0f / 65536.0f);
                acc -= (double)(pf * __logf(pf + 1e-8f));
            }
        }
    }
    // correction: cells with J>0, counted once (first pixel with that key)
    int myk = key[t], n = 0; bool first = true;
    for (int p = 0; p < 256; ++p) {
        int k2 = key[p];
        if (k2 == myk) { n++; if (p < t) first = false; }
    }
    if (first) {
        int cnt = 2 * n + 256 - hms[myk >> 8] - hp[myk & 255];
        float pf = (float)cnt * (1.0f / 65536.0f);
        acc -= (double)(pf * __logf(pf + 1e-8f));
    }
    double h = blockSumD(acc, red4);
    if (t == 0) hjoint[b * CC + c] = (float)h;
}

// ---------- K7: mi softmax + rel_ms ----------
__global__ __launch_bounds__(256) void k7_relms(const float* __restrict__ fms,
                                                const float* __restrict__ hmsE,
                                                const float* __restrict__ hpE,
                                                const float* __restrict__ hjoint,
                                                float* __restrict__ out2) {
    int b = blockIdx.x, t = threadIdx.x;
    __shared__ double mi[64];
    if (t < 64) mi[t] = (double)hpE[b] + (double)hmsE[b * CC + t] - (double)hjoint[b * CC + t];
    __syncthreads();
    if (t == 0) {
        double mxv = mi[0];
        for (int c2 = 1; c2 < 64; ++c2) if (mi[c2] > mxv) mxv = mi[c2];
        double s = 0.0;
        for (int c2 = 0; c2 < 64; ++c2) { mi[c2] = exp(mi[c2] - mxv); s += mi[c2]; }
        for (int c2 = 0; c2 < 64; ++c2) mi[c2] /= s;
    }
    __syncthreads();
    const float* src = fms + (size_t)b * CC * QQ;
    float* dst = out2 + (size_t)b * CC * QQ;
    for (int e = t; e < CC * QQ; e += 256) {
        float v = src[e];
        float miv = (float)mi[e >> 8];
        dst[e] = v + v * miv;
    }
}

// ---------- K8: similarity row max/argmax per (b,c) ----------
__global__ __launch_bounds__(256) void k8_smax(const float* __restrict__ fms,
                                               const float* __restrict__ gtent,
                                               const float* __restrict__ mssum,
                                               const float* __restrict__ chsum,
                                               const float* __restrict__ chsumsq,
                                               const float* __restrict__ naArr,
                                               float* __restrict__ mxArr,
                                               int* __restrict__ idxArr) {
    int blk = blockIdx.x, b = blk >> 6, c = blk & 63, t = threadIdx.x;
    __shared__ float msrow[256];
    __shared__ double part[256];
    __shared__ double sval[64];
    msrow[t] = fms[(size_t)(b * CC + c) * QQ + t];
    __syncthreads();
    int d = t >> 2, pr = t & 3;
    const float* g = gtent + (size_t)(b * CC + d) * QQ + pr * 64;
    const float* mr = msrow + pr * 64;
    double acc = 0.0;
    for (int q2 = 0; q2 < 64; ++q2) acc += (double)mr[q2] * (double)g[q2];
    part[t] = acc;
    __syncthreads();
    if (t < 64) {
        double meanu = (double)mssum[b * CC + c] * (1.0 / 256.0);
        double meanp = (double)chsum[b * CC + t] * (1.0 / 65536.0);
        sval[t] = part[t * 4] + part[t * 4 + 1] + part[t * 4 + 2] + part[t * 4 + 3]
                  - 65536.0 * meanu * meanp;
    }
    __syncthreads();
    if (t == 0) {
        double best = sval[0]; int bi2 = 0;
        for (int dd = 1; dd < 64; ++dd) { if (sval[dd] > best) { best = sval[dd]; bi2 = dd; } }
        double nac = (double)naArr[b * CC + c];
        double sc_ = (double)chsum[b * CC + c];
        double sq_ = (double)chsumsq[b * CC + c];
        double nb2 = sq_ - sc_ * sc_ * (1.0 / 65536.0);
        double nbc = sqrt(nb2 > 0.0 ? nb2 : 0.0);
        mxArr[b * CC + c] = (float)(best * 100.0 / (nac * nbc));
        idxArr[b * CC + c] = bi2;
    }
}

// ---------- K9: scores, grouping, min_k, stable sort, selection weights ----------
// One block, 512 threads = 8 batches x 64 channels (one wave per batch).
__global__ __launch_bounds__(512) void k9_small(const float* __restrict__ mxArr,
                                                const int* __restrict__ idxArr,
                                                float* __restrict__ wsel,
                                                int* __restrict__ chanA,
                                                int* __restrict__ minkA) {
    __shared__ double sc[8][64];
    __shared__ double gs[8][64];
    __shared__ int idxS[8][64];
    __shared__ int ordv[8][64];
    __shared__ int uarr[8];
    __shared__ int mkS;
    int t = threadIdx.x;
    int b = t >> 6, c = t & 63;
    double v = (double)mxArr[b * 64 + c];
    // wave softmax over the 64 channels of batch b
    double mx = v;
    for (int d = 32; d; d >>= 1) mx = fmax(mx, __shfl_down(mx, d, 64));
    mx = __shfl(mx, 0, 64);
    double e = exp(v - mx);
    double s = e;
    for (int d = 32; d; d >>= 1) s += __shfl_down(s, d, 64);
    s = __shfl(s, 0, 64);
    sc[b][c] = e / s;
    idxS[b][c] = idxArr[b * 64 + c];
    __syncthreads();
    // group score for group c: scan in index order (deterministic, matches
    // the serial scatter-add order of the reference)
    double g = 0.0; int cnt = 0;
    for (int c2 = 0; c2 < 64; ++c2) {
        if (idxS[b][c2] == c) { g += sc[b][c2]; cnt++; }
    }
    gs[b][c] = g;
    unsigned long long ball = __ballot(cnt > 0);
    if (c == 0) uarr[b] = __popcll(ball);
    __syncthreads();
    if (t == 0) {
        int k = uarr[0];
        for (int b2 = 1; b2 < 8; ++b2) k = min(k, uarr[b2]);
        mkS = (k + 1) >> 1;
        minkA[0] = mkS;
    }
    __syncthreads();
    // stable descending rank: ties -> smaller index first
    int rk = 0;
    double myg = gs[b][c];
    for (int c3 = 0; c3 < 64; ++c3) {
        double a = gs[b][c3];
        if (a > myg || (a == myg && c3 < c)) rk++;
    }
    ordv[b][rk] = c;
    __syncthreads();
    int mk = mkS;
    double z0 = gs[b][ordv[b][0]];
    double ee = (c < mk) ? exp(gs[b][ordv[b][c]] - z0) : 0.0;
    double se = ee;
    for (int d = 32; d; d >>= 1) se += __shfl_down(se, d, 64);
    se = __shfl(se, 0, 64);
    if (c < mk) {
        wsel[b * 64 + c] = (float)(ee / se);
        chanA[b * 64 + c] = ordv[b][c];
    }
}

// ---------- K10: rel_p = f_p * (1 + mask) ----------
__global__ __launch_bounds__(256) void k10_relp(const float* __restrict__ fp,
                                                const float* __restrict__ wsel,
                                                const int* __restrict__ chanA,
                                                const int* __restrict__ minkA,
                                                float* __restrict__ outp) {
    int b = blockIdx.y;
    int i4 = blockIdx.x * 256 + threadIdx.x;      // [0, P/4)
    int mk = minkA[0];
    const float4* src = (const float4*)(fp + (size_t)b * CC * PP);
    float mx0 = 0.f, mx1 = 0.f, mx2 = 0.f, mx3 = 0.f;
    for (int i = 0; i < mk; ++i) {
        int ch = chanA[b * 64 + i];
        float wv = wsel[b * 64 + i];
        float4 v = src[(size_t)ch * (PP / 4) + i4];
        mx0 += wv * (1.0f / (1.0f + __expf(-v.x)));
        mx1 += wv * (1.0f / (1.0f + __expf(-v.y)));
        mx2 += wv * (1.0f / (1.0f + __expf(-v.z)));
        mx3 += wv * (1.0f / (1.0f + __expf(-v.w)));
    }
    float4* dst = (float4*)(outp + (size_t)b * CC * PP);
    for (int c2 = 0; c2 < CC; ++c2) {
        float4 v = src[(size_t)c2 * (PP / 4) + i4];
        float4 o;
        o.x = v.x + v.x * mx0;
        o.y = v.y + v.y * mx1;
        o.z = v.z + v.z * mx2;
        o.w = v.w + v.w * mx3;
        dst[(size_t)c2 * (PP / 4) + i4] = o;
    }
}

extern "C" void kernel_launch(void* const* d_in, const int* in_sizes, int n_in,
                              void* d_out, int out_size, void* d_ws, size_t ws_size,
                              hipStream_t stream) {
    const float* fp = (const float*)d_in[0];   // [8,64,256,256]
    const float* fms = (const float*)d_in[1];  // [8,64,16,16]
    float* out = (float*)d_out;

    char* p = (char*)d_ws;
    auto alloc = [&](size_t bytes) { void* r = (void*)p; p += (bytes + 255) & ~(size_t)255; return r; };

    float* fpm      = (float*)alloc((size_t)BB * PP * 4);        // 2 MB
    float* cellsum  = (float*)alloc((size_t)BB * CC * QQ * 4);   // 512 KB (block SUMS)
    float* gtent    = (float*)alloc((size_t)BB * CC * QQ * 4);   // 512 KB
    float* chsum    = (float*)alloc((size_t)BB * CC * 4);
    float* chsumsq  = (float*)alloc((size_t)BB * CC * 4);
    unsigned* minmax= (unsigned*)alloc((size_t)BB * 2 * 4);
    int* histpm     = (int*)alloc((size_t)BB * 256 * 4);
    int* msn        = (int*)alloc((size_t)BB * CC * QQ * 4);     // 512 KB
    int* histms     = (int*)alloc((size_t)BB * CC * 256 * 4);    // 512 KB
    int* histp      = (int*)alloc((size_t)BB * 256 * 4);
    int* pan        = (int*)alloc((size_t)BB * QQ * 4);
    float* hmsE     = (float*)alloc((size_t)BB * CC * 4);
    float* hpE      = (float*)alloc((size_t)BB * 4);
    float* hjoint   = (float*)alloc((size_t)BB * CC * 4);
    float* naArr    = (float*)alloc((size_t)BB * CC * 4);
    float* mssum    = (float*)alloc((size_t)BB * CC * 4);
    float* mxArr    = (float*)alloc((size_t)BB * CC * 4);
    int* idxArr     = (int*)alloc((size_t)BB * CC * 4);
    float* wsel     = (float*)alloc((size_t)BB * CC * 4);
    int* chanA      = (int*)alloc((size_t)BB * CC * 4);
    int* minkA      = (int*)alloc(256);

    float* out_relp  = out;                                      // [8,64,256,256]
    float* out_relms = out + (size_t)BB * CC * PP;               // [8,64,16,16]

    k0_init<<<8, 256, 0, stream>>>(minmax, histpm);
    k1_fpm<<<dim3(64, 8), 256, 0, stream>>>(fp, fpm, minmax);
    k2a_hist<<<dim3(64, 8), 256, 0, stream>>>(fpm, minmax, histpm);
    k2b_entropy<<<8, 256, 0, stream>>>(histpm, hpE);
    k3_chan<<<512, 256, 0, stream>>>(fp, cellsum, gtent, chsum, chsumsq);
    k4_ms<<<512, 256, 0, stream>>>(fms, msn, histms, hmsE, naArr, mssum);
    k5_pa<<<8, 256, 0, stream>>>(cellsum, pan, histp);
    k6_joint<<<512, 256, 0, stream>>>(msn, pan, histms, histp, hjoint);
    k7_relms<<<8, 256, 0, stream>>>(fms, hmsE, hpE, hjoint, out_relms);
    k8_smax<<<512, 256, 0, stream>>>(fms, gtent, mssum, chsum, chsumsq, naArr, mxArr, idxArr);
    k9_small<<<1, 512, 0, stream>>>(mxArr, idxArr, wsel, chanA, minkA);
    k10_relp<<<dim3(64, 8), 256, 0, stream>>>(fp, wsel, chanA, minkA, out_relp);
}